// Round 5
// baseline (534.684 us; speedup 1.0000x reference)
//
#include <hip/hip_runtime.h>
#include <stdint.h>

typedef unsigned int u32;
typedef __bf16 bf16_t;
typedef bf16_t bf16x8 __attribute__((ext_vector_type(8)));
typedef bf16_t bf16x4 __attribute__((ext_vector_type(4)));
typedef float  f32x4  __attribute__((ext_vector_type(4)));

#define NB   256
#define NN   196
#define CD   2048
#define QD   1024
#define NE   1024
#define NG   8

// workspace layout (bytes)
#define WS_QP    0
#define WS_ATTN  (NB*NE*4)                              // 1,048,576
#define WS_WCB   (WS_ATTN + NB*NG*NN*4)                 // 2,654,208
#define WS_CTXB  (WS_WCB + (size_t)NE*CD*2)             // 6,848,512
#define WS_NEED  (WS_CTXB + (size_t)NB*NN*CD*2)         // 212,369,408

__device__ __forceinline__ bf16_t f2bf(float f){
  u32 u = __float_as_uint(f);
  u += 0x7fffu + ((u >> 16) & 1u);            // RNE
  unsigned short h = (unsigned short)(u >> 16);
  return __builtin_bit_cast(bf16_t, h);
}

__device__ __forceinline__ float fast_tanh(float x){
  float e = __expf(2.0f * x);
  return 1.0f - 2.0f / (e + 1.0f);
}

__device__ __forceinline__ void load_lds16(const void* g, void* l){
  __builtin_amdgcn_global_load_lds(
      (const __attribute__((address_space(1))) void*)g,
      (__attribute__((address_space(3))) void*)l, 16, 0, 0);
}

// ---------------- Wc f32 -> bf16 ----------------
__global__ __launch_bounds__(256)
void k_conv(const float* __restrict__ src, bf16_t* __restrict__ dst){
  size_t i = ((size_t)blockIdx.x * 256 + threadIdx.x) * 4;
  float4 v = *(const float4*)(src + i);
  bf16x4 o = { f2bf(v.x), f2bf(v.y), f2bf(v.z), f2bf(v.w) };
  *(bf16x4*)(dst + i) = o;
}

// ---------------- ctx f32 -> bf16 (8 elems/thread) ----------------
__global__ __launch_bounds__(256)
void k_convctx(const float* __restrict__ src, bf16_t* __restrict__ dst){
  size_t i = ((size_t)blockIdx.x * 256 + threadIdx.x) * 8;
  float4 a = *(const float4*)(src + i);
  float4 b = *(const float4*)(src + i + 4);
  bf16x8 o = { f2bf(a.x), f2bf(a.y), f2bf(a.z), f2bf(a.w),
               f2bf(b.x), f2bf(b.y), f2bf(b.z), f2bf(b.w) };
  *(bf16x8*)(dst + i) = o;
}

// ---------------- qp = query @ Wq^T + bq  (f32, 32x32 tiles) ----------------
__global__ __launch_bounds__(256)
void k_qp(const float* __restrict__ query, const float* __restrict__ Wq,
          const float* __restrict__ bq, float* __restrict__ qp){
  __shared__ float qs[32][36];
  __shared__ float wsm[32][36];
  const u32 t  = threadIdx.x;
  const u32 e0 = blockIdx.x * 32, b0 = blockIdx.y * 32;
  const u32 r  = t >> 3, ci = (t & 7) * 4;
  const u32 tm = (t >> 4) * 2, tn = (t & 15) * 2;
  float c00 = 0.f, c01 = 0.f, c10 = 0.f, c11 = 0.f;
  for (u32 k0 = 0; k0 < QD; k0 += 32){
    float4 qv = *(const float4*)(query + (size_t)(b0 + r) * QD + k0 + ci);
    float4 wv = *(const float4*)(Wq    + (size_t)(e0 + r) * QD + k0 + ci);
    __syncthreads();
    *(float4*)&qs[r][ci]  = qv;
    *(float4*)&wsm[r][ci] = wv;
    __syncthreads();
    #pragma unroll
    for (int kq = 0; kq < 8; kq++){
      float4 a0 = *(const float4*)&qs[tm][kq*4];
      float4 a1 = *(const float4*)&qs[tm+1][kq*4];
      float4 b0v = *(const float4*)&wsm[tn][kq*4];
      float4 b1v = *(const float4*)&wsm[tn+1][kq*4];
      c00 += a0.x*b0v.x + a0.y*b0v.y + a0.z*b0v.z + a0.w*b0v.w;
      c01 += a0.x*b1v.x + a0.y*b1v.y + a0.z*b1v.z + a0.w*b1v.w;
      c10 += a1.x*b0v.x + a1.y*b0v.y + a1.z*b0v.z + a1.w*b0v.w;
      c11 += a1.x*b1v.x + a1.y*b1v.y + a1.z*b1v.z + a1.w*b1v.w;
    }
  }
  float bq0 = bq[e0+tn], bq1 = bq[e0+tn+1];
  qp[(size_t)(b0+tm  )*NE + e0+tn  ] = c00 + bq0;
  qp[(size_t)(b0+tm  )*NE + e0+tn+1] = c01 + bq1;
  qp[(size_t)(b0+tm+1)*NE + e0+tn  ] = c10 + bq0;
  qp[(size_t)(b0+tm+1)*NE + e0+tn+1] = c11 + bq1;
}

// ================= 8-phase 256x256 main GEMM + fused epilogue =================
// LDS K-loop: buf b at b*65536: A 256x(64 elem = 8 x 16B slots, XOR-swizzled) @0,
//             B same @32768. Epilogue overlay: comb[256][256] bf16 swizzled @0;
//             qps[3][256] f32 @131072; bcs[256] f32 @134144. Total 135168 B.
#define NKT 32   // 2048/64

__global__ __launch_bounds__(512, 2)
void k_main8(const bf16_t* __restrict__ ctxb, const bf16_t* __restrict__ wcb,
             const float* __restrict__ qp, const float* __restrict__ bcv,
             const float* __restrict__ Wo, float* __restrict__ attn)
{
  __shared__ char smem[135168] __attribute__((aligned(128)));

  const u32 tid  = threadIdx.x;
  const u32 lane = tid & 63;
  const u32 w    = tid >> 6;          // wave 0..7
  const u32 q    = lane >> 4;         // 0..3
  const u32 r15  = lane & 15;
  const u32 x7   = r15 & 7;           // read-side XOR

  // bijective XCD swizzle: grid 784 = 8 * 98
  u32 d  = blockIdx.x;
  u32 wg = (d & 7) * 98u + (d >> 3);
  const u32 ms = wg >> 2;             // 0..195
  const u32 ec = wg & 3;              // 0..3
  const u32 m0 = ms * 256;
  const u32 e0 = ec * 256;

  // staging constants: half-tile = 128 rows x 128 B; 2 issues x (512 thr x 16B)
  // thread covers row_local = i*64 + w*8 + (lane>>3), phys slot = lane&7,
  // source 16B-quarter = slot ^ (row&7)  (both-sides involution)
  const u32 srow = w*8 + (lane>>3);                      // 0..63
  const u32 scol = ((lane&7) ^ ((lane>>3)&7)) * 8;       // source elem offset
  const u32 sdst = w*1024u + lane*16u;

  const u32 arow = (w>>1)*32 + r15;   // A-frag row base within quadrant rows
  const u32 brow = (w&1)*64 + r15;    // B-frag row base within quadrant cols

  f32x4 acc[2][2][8];
  #pragma unroll
  for (int a1 = 0; a1 < 2; a1++)
    #pragma unroll
    for (int a2 = 0; a2 < 2; a2++)
      #pragma unroll
      for (int a3 = 0; a3 < 8; a3++) acc[a1][a2][a3] = (f32x4){0.f,0.f,0.f,0.f};

  // half index H: tile = H>>2, half = H&3 (0=A0,1=A1,2=B0,3=B1), buf = tile&1
  auto stage = [&](u32 H){
    u32 tile = H >> 2;
    u32 half = H & 3;
    u32 kt   = tile < NKT ? tile : (NKT - 1);   // clamp (dummy loads at tail)
    u32 buf  = tile & 1;
    u32 isb  = half >> 1;
    u32 hh   = half & 1;
    const bf16_t* src = (isb ? (wcb + (size_t)e0 * CD) : (ctxb + (size_t)m0 * CD))
                        + (size_t)(hh*128u + srow) * CD + kt*64u + scol;
    char* dst = smem + buf*65536u + isb*32768u + hh*16384u + sdst;
    load_lds16(src,                  dst);
    load_lds16(src + (size_t)64*CD,  dst + 8192);
  };

  // prologue: A0(0),A1(0),B0(0),B1(0),A0(1)  (10 loads), then counted wait
  stage(0); stage(1); stage(2); stage(3); stage(4);
  asm volatile("s_waitcnt vmcnt(4)" ::: "memory");
  __builtin_amdgcn_s_barrier();

#define PHASE(QM, QN, HOFF, DOVM) do {                                          \
    const char* Ab_ = smem + bufc*65536u;                                        \
    const char* Bb_ = Ab_ + 32768u;                                              \
    bf16x8 af[2][2], bq_[4][2];                                                  \
    _Pragma("unroll")                                                            \
    for (int m2 = 0; m2 < 2; m2++)                                               \
      _Pragma("unroll")                                                          \
      for (int kk = 0; kk < 2; kk++)                                             \
        af[m2][kk] = *(const bf16x8*)(Ab_ + ((QM)*128u + arow + m2*16u)*128u     \
                                          + (((u32)(kk*4) + q) ^ x7)*16u);       \
    _Pragma("unroll")                                                            \
    for (int nt = 0; nt < 4; nt++)                                               \
      _Pragma("unroll")                                                          \
      for (int kk = 0; kk < 2; kk++)                                             \
        bq_[nt][kk] = *(const bf16x8*)(Bb_ + ((QN)*128u + brow + nt*16u)*128u    \
                                           + (((u32)(kk*4) + q) ^ x7)*16u);      \
    stage(hbase + (HOFF));                                                       \
    __builtin_amdgcn_s_barrier();                                                \
    __builtin_amdgcn_s_setprio(1);                                               \
    _Pragma("unroll")                                                            \
    for (int m2 = 0; m2 < 2; m2++)                                               \
      _Pragma("unroll")                                                          \
      for (int nt = 0; nt < 4; nt++)                                             \
        _Pragma("unroll")                                                        \
        for (int kk = 0; kk < 2; kk++)                                           \
          acc[QM][QN][m2*4+nt] = __builtin_amdgcn_mfma_f32_16x16x32_bf16(        \
              af[m2][kk], bq_[nt][kk], acc[QM][QN][m2*4+nt], 0, 0, 0);           \
    __builtin_amdgcn_s_setprio(0);                                               \
    if (DOVM) asm volatile("s_waitcnt vmcnt(4)" ::: "memory");                   \
    __builtin_amdgcn_s_barrier();                                                \
  } while (0)

  for (u32 kt = 0; kt < NKT; kt++){
    const u32 bufc  = kt & 1;
    const u32 hbase = 4*kt + 5;
    PHASE(0, 0, 0, 1);   // reads A0,B0 ; stages A1(kt+1) ; vm-gate for p1
    PHASE(0, 1, 1, 0);   // reads A0,B1 ; stages B0(kt+1)
    PHASE(1, 0, 2, 0);   // reads A1,B0 ; stages B1(kt+1)
    PHASE(1, 1, 3, 1);   // reads A1,B1 ; stages A0(kt+2) ; vm-gate for next p0
  }
#undef PHASE

  // drain outstanding (dummy) DMAs before overlaying LDS
  asm volatile("s_waitcnt vmcnt(0)" ::: "memory");
  __syncthreads();

  // ---------------- epilogue: tanh + attn partial ----------------
  float*  qps  = (float*)(smem + 131072);   // [3][256]
  float*  bcs  = (float*)(smem + 134144);   // [256]
  const u32 b0   = m0 / 196u;
  const u32 bnd1 = (b0 + 1) * 196u - m0;
  const u32 bnd2 = bnd1 + 196u;

  for (u32 idx = tid; idx < 768; idx += 512){
    u32 bb = b0 + idx / 256u;
    if (bb > NB - 1) bb = NB - 1;
    qps[idx] = qp[(size_t)bb * NE + e0 + (idx & 255u)];
  }
  if (tid < 256) bcs[tid] = bcv[e0 + tid];

  // Wo fragments: A-operand rows g=r15 (<8 valid), k=e
  bf16x8 wf[8];
  {
    u32 g = r15;
    #pragma unroll
    for (int kk = 0; kk < 8; kk++){
      #pragma unroll
      for (int rr = 0; rr < 8; rr++){
        u32 ei = e0 + kk*32 + q*8 + rr;
        float v = (g < NG) ? Wo[(size_t)g * NE + ei] : 0.0f;
        wf[kk][rr] = f2bf(v);
      }
    }
  }
  __syncthreads();

  // tanh(cp + qp + bc) -> comb (swizzled [256][256] bf16 over smem base)
  #pragma unroll
  for (int qm = 0; qm < 2; qm++)
    #pragma unroll
    for (int qn = 0; qn < 2; qn++)
      #pragma unroll
      for (int t = 0; t < 8; t++){
        u32 rowb = qm*128u + (w>>1)*32u + (t>>2)*16u + q*4u;
        u32 col  = qn*128u + (w&1)*64u + (t&3)*16u + r15;
        float qb = bcs[col];
        #pragma unroll
        for (int r = 0; r < 4; r++){
          u32 row = rowb + r;
          u32 bidx = (row >= bnd1 ? 1u : 0u) + (row >= bnd2 ? 1u : 0u);
          float v = fast_tanh(acc[qm][qn][t][r] + qps[bidx*256u + col] + qb);
          u32 phys = (col >> 3) ^ (row & 7);
          *(bf16_t*)(smem + row*512u + phys*16u + (col&7)*2u) = f2bf(v);
        }
      }
  __syncthreads();

  // attn^T[g][n] = sum_e Wo[g,e]*comb[n,e]; 2 row-tiles of 16 per wave
  #pragma unroll
  for (int i = 0; i < 2; i++){
    u32 nrow = w*32u + i*16u + r15;
    f32x4 at = (f32x4){0.f,0.f,0.f,0.f};
    #pragma unroll
    for (int kk = 0; kk < 8; kk++){
      u32 phys = ((u32)(kk*4) + q) ^ (nrow & 7);
      bf16x8 cf = *(const bf16x8*)(smem + nrow*512u + phys*16u);
      at = __builtin_amdgcn_mfma_f32_16x16x32_bf16(wf[kk], cf, at, 0, 0, 0);
    }
    if (q < 2){
      u32 mrow = m0 + nrow;
      u32 bb = mrow / 196u;
      u32 nn = mrow - bb * 196u;
      #pragma unroll
      for (int r = 0; r < 4; r++){
        u32 g = q*4 + r;
        atomicAdd(&attn[((size_t)bb * NG + g) * NN + nn], at[r]);
      }
    }
  }
}

// ---------------- SLOW fallback main (reg-staged f32 ctx, 128 tile) ----------
#define BM 128
#define BN 128
#define BK 32
#define KSTEPS (CD/BK)

__global__ __launch_bounds__(256, 2)
void k_main_slow(const float* __restrict__ ctx, const bf16_t* __restrict__ wcb,
                 const float* __restrict__ qp, const float* __restrict__ bcv,
                 const float* __restrict__ Wo, float* __restrict__ attn)
{
  __shared__ char smem[40960] __attribute__((aligned(16)));
  const u32 tid  = threadIdx.x;
  const u32 lane = tid & 63;
  const u32 wave = tid >> 6;
  const u32 wm   = wave >> 1;
  const u32 wn   = wave & 1;
  u32 d  = blockIdx.x;
  u32 x  = d & 7;
  u32 s  = d >> 3;
  u32 ec = s & 7;
  u32 j  = s >> 3;
  u32 ms = j * 8 + x;
  const u32 m0 = ms * BM;
  const u32 e0 = ec * BN;
  const u32 ar  = tid >> 3;
  const u32 ac  = (tid & 7) * 4;
  const u32 br  = tid >> 2;
  const u32 bc8 = (tid & 3) * 8;
  const float*  actx = ctx + (size_t)m0 * CD;
  const bf16_t* bwc  = wcb + (size_t)e0 * CD;
  float4 av[4];
  uint4  bv[2];
  f32x4 acc[4][4];
  #pragma unroll
  for (int i = 0; i < 4; i++)
    #pragma unroll
    for (int jn = 0; jn < 4; jn++) acc[i][jn] = (f32x4){0.f,0.f,0.f,0.f};
  auto issue = [&](u32 ks){
    const u32 k0 = ks * BK;
    #pragma unroll
    for (int p = 0; p < 4; p++)
      av[p] = *(const float4*)(actx + (size_t)(ar + p*32) * CD + k0 + ac);
    #pragma unroll
    for (int p = 0; p < 2; p++)
      bv[p] = *(const uint4*)(bwc + (size_t)(br + p*64) * CD + k0 + bc8);
  };
  auto writebuf = [&](u32 buf){
    bf16_t* A  = (bf16_t*)(smem + buf * 10240u);
    bf16_t* Bb = (bf16_t*)(smem + 20480u + buf * 10240u);
    #pragma unroll
    for (int p = 0; p < 4; p++){
      bf16x4 o = { f2bf(av[p].x), f2bf(av[p].y), f2bf(av[p].z), f2bf(av[p].w) };
      *(bf16x4*)&A[(ar + p*32)*40 + ac] = o;
    }
    #pragma unroll
    for (int p = 0; p < 2; p++)
      *(uint4*)&Bb[(br + p*64)*40 + bc8] = bv[p];
  };
  auto compute = [&](u32 buf){
    bf16_t* A  = (bf16_t*)(smem + buf * 10240u);
    bf16_t* Bb = (bf16_t*)(smem + 20480u + buf * 10240u);
    const u32 kb = (lane >> 4) * 8;
    const u32 rm = wm*64 + (lane & 15);
    const u32 rn = wn*64 + (lane & 15);
    bf16x8 af[4], bfr[4];
    #pragma unroll
    for (int mt = 0; mt < 4; mt++) af[mt]  = *(const bf16x8*)&A[(rm + mt*16)*40 + kb];
    #pragma unroll
    for (int nt = 0; nt < 4; nt++) bfr[nt] = *(const bf16x8*)&Bb[(rn + nt*16)*40 + kb];
    #pragma unroll
    for (int mt = 0; mt < 4; mt++)
      #pragma unroll
      for (int nt = 0; nt < 4; nt++)
        acc[mt][nt] = __builtin_amdgcn_mfma_f32_16x16x32_bf16(af[mt], bfr[nt], acc[mt][nt], 0, 0, 0);
  };
  issue(0); writebuf(0);
  __syncthreads();
  for (u32 ks = 0; ks < KSTEPS; ks++){
    if (ks + 1 < KSTEPS) issue(ks + 1);
    compute(ks & 1);
    __syncthreads();
    if (ks + 1 < KSTEPS){
      writebuf((ks + 1) & 1);
      __syncthreads();
    }
  }
  float*  qp0  = (float*)(smem + 35840);
  float*  qp1  = (float*)(smem + 36352);
  float*  bcs  = (float*)(smem + 36864);
  bf16_t* comb = (bf16_t*)smem;
  const u32 b0  = m0 / 196u;
  const u32 bnd = (b0 + 1) * 196u - m0;
  if (tid < 128){
    qp0[tid] = qp[(size_t)b0 * NE + e0 + tid];
    bcs[tid] = bcv[e0 + tid];
  } else {
    u32 b1 = b0 + 1; if (b1 >= NB) b1 = NB - 1;
    qp1[tid - 128] = qp[(size_t)b1 * NE + e0 + (tid - 128)];
  }
  bf16x8 wf[4];
  {
    u32 g = lane & 15;
    #pragma unroll
    for (int kk = 0; kk < 4; kk++){
      #pragma unroll
      for (int rr = 0; rr < 8; rr++){
        u32 ei = e0 + kk*32 + (lane >> 4)*8 + rr;
        float v = (g < NG) ? Wo[(size_t)g * NE + ei] : 0.0f;
        wf[kk][rr] = f2bf(v);
      }
    }
  }
  __syncthreads();
  #pragma unroll
  for (int nt = 0; nt < 4; nt++){
    u32 el = wn*64 + nt*16 + (lane & 15);
    float qa = qp0[el];
    float qb = qp1[el];
    float bcx = bcs[el];
    #pragma unroll
    for (int mt = 0; mt < 4; mt++){
      u32 rl = wm*64 + mt*16 + (lane >> 4)*4;
      #pragma unroll
      for (int r = 0; r < 4; r++){
        u32 row = rl + r;
        float qv = (row >= bnd) ? qb : qa;
        float t = fast_tanh(acc[mt][nt][r] + qv + bcx);
        comb[row*136 + el] = f2bf(t);
      }
    }
  }
  __syncthreads();
  #pragma unroll
  for (int i = 0; i < 2; i++){
    u32 nrow = (wave*2 + i)*16 + (lane & 15);
    f32x4 at = (f32x4){0.f,0.f,0.f,0.f};
    #pragma unroll
    for (int kk = 0; kk < 4; kk++){
      bf16x8 cf = *(const bf16x8*)&comb[nrow*136 + kk*32 + (lane >> 4)*8];
      at = __builtin_amdgcn_mfma_f32_16x16x32_bf16(wf[kk], cf, at, 0, 0, 0);
    }
    if ((lane >> 4) < 2){
      u32 mrow = m0 + nrow;
      u32 bb = mrow / 196u;
      u32 nn = mrow - bb * 196u;
      #pragma unroll
      for (int r = 0; r < 4; r++){
        u32 g = (lane >> 4)*4 + r;
        atomicAdd(&attn[((size_t)bb * NG + g) * NN + nn], at[r]);
      }
    }
  }
}

// ---------------- softmax over n per (b,g) ----------------
__global__ __launch_bounds__(256)
void k_softmax(float* __restrict__ attn){
  u32 flat = blockIdx.x * 4 + (threadIdx.x >> 6);
  u32 lane = threadIdx.x & 63;
  float* row = attn + (size_t)flat * NN;
  float v0 = row[lane];
  float v1 = row[lane + 64];
  float v2 = row[lane + 128];
  float v3 = (lane < 4) ? row[lane + 192] : -1e30f;
  float m = fmaxf(fmaxf(v0, v1), fmaxf(v2, v3));
  #pragma unroll
  for (int o = 1; o < 64; o <<= 1) m = fmaxf(m, __shfl_xor(m, o));
  float e0 = __expf(v0 - m), e1 = __expf(v1 - m), e2 = __expf(v2 - m);
  float e3 = (lane < 4) ? __expf(v3 - m) : 0.f;
  float sum = e0 + e1 + e2 + e3;
  #pragma unroll
  for (int o = 1; o < 64; o <<= 1) sum += __shfl_xor(sum, o);
  float inv = 1.0f / sum;
  row[lane]       = e0 * inv;
  row[lane + 64]  = e1 * inv;
  row[lane + 128] = e2 * inv;
  if (lane < 4) row[lane + 192] = e3 * inv;
}

// ---------------- glimpse: out[b,g,c] = sum_n w[b,g,n]*ctx[b,n,c] ----------------
__global__ __launch_bounds__(256)
void k_glimpse(const float* __restrict__ ctx, const float* __restrict__ w,
               float* __restrict__ out){
  const u32 b  = blockIdx.y;
  const u32 c0 = blockIdx.x * 512 + threadIdx.x * 2;
  __shared__ float ws_[NG * NN];
  for (u32 i = threadIdx.x; i < NG * NN; i += 256)
    ws_[i] = w[(size_t)b * NG * NN + i];
  __syncthreads();
  const float* cp = ctx + (size_t)b * NN * CD + c0;
  float2 acc[NG];
  #pragma unroll
  for (int g = 0; g < NG; g++) acc[g] = make_float2(0.f, 0.f);
  for (u32 n = 0; n < NN; n++){
    float2 v = *(const float2*)(cp + (size_t)n * CD);
    #pragma unroll
    for (int g = 0; g < NG; g++){
      float wv = ws_[g * NN + n];
      acc[g].x = fmaf(wv, v.x, acc[g].x);
      acc[g].y = fmaf(wv, v.y, acc[g].y);
    }
  }
  #pragma unroll
  for (int g = 0; g < NG; g++)
    *(float2*)(out + (size_t)b * (NG * CD) + (size_t)g * CD + c0) = acc[g];
}

extern "C" void kernel_launch(void* const* d_in, const int* in_sizes, int n_in,
                              void* d_out, int out_size, void* d_ws, size_t ws_size,
                              hipStream_t stream)
{
  const float* ctx   = (const float*)d_in[0];
  const float* query = (const float*)d_in[1];
  const float* Wq    = (const float*)d_in[2];
  const float* bq    = (const float*)d_in[3];
  const float* Wc    = (const float*)d_in[4];
  const float* bc    = (const float*)d_in[5];
  const float* Wo    = (const float*)d_in[6];
  // d_in[7] = bo: constant over softmax axis -> cancels, unused.

  char* ws = (char*)d_ws;
  float*  qp   = (float*)(ws + WS_QP);
  float*  attn = (float*)(ws + WS_ATTN);
  bf16_t* wcb  = (bf16_t*)(ws + WS_WCB);
  bf16_t* ctxb = (bf16_t*)(ws + WS_CTXB);
  float*  out  = (float*)d_out;

  (void)hipMemsetAsync(attn, 0, (size_t)NB * NG * NN * 4, stream);
  k_conv<<<2048, 256, 0, stream>>>(Wc, wcb);
  k_qp<<<dim3(32, 8), 256, 0, stream>>>(query, Wq, bq, qp);

  if (ws_size >= (size_t)WS_NEED){
    k_convctx<<<50176, 256, 0, stream>>>(ctx, ctxb);
    k_main8<<<784, 512, 0, stream>>>(ctxb, wcb, qp, bc, Wo, attn);
  } else {
    k_main_slow<<<3136, 256, 0, stream>>>(ctx, wcb, qp, bc, Wo, attn);
  }

  k_softmax<<<512, 256, 0, stream>>>(attn);
  k_glimpse<<<dim3(4, 256), 256, 0, stream>>>(ctx, attn, out);
}

// Round 6
// 507.856 us; speedup vs baseline: 1.0528x; 1.0528x over previous
//
#include <hip/hip_runtime.h>
#include <stdint.h>

typedef unsigned int u32;
typedef __bf16 bf16_t;
typedef bf16_t bf16x8 __attribute__((ext_vector_type(8)));
typedef bf16_t bf16x4 __attribute__((ext_vector_type(4)));
typedef float  f32x4  __attribute__((ext_vector_type(4)));

#define NB   256
#define NN   196
#define CD   2048
#define QD   1024
#define NE   1024
#define NG   8

// workspace layout (bytes)
#define WS_QP    0
#define WS_ATTN  (NB*NE*4)                              // 1,048,576
#define WS_WCB   (WS_ATTN + NB*NG*NN*4)                 // 2,654,208
#define WS_CTXB  (WS_WCB + (size_t)NE*CD*2)             // 6,848,512
#define WS_NEED  (WS_CTXB + (size_t)NB*NN*CD*2)         // 212,369,408

__device__ __forceinline__ bf16_t f2bf(float f){
  u32 u = __float_as_uint(f);
  u += 0x7fffu + ((u >> 16) & 1u);            // RNE
  unsigned short h = (unsigned short)(u >> 16);
  return __builtin_bit_cast(bf16_t, h);
}

__device__ __forceinline__ float fast_tanh(float x){
  float e = __expf(2.0f * x);
  return 1.0f - 2.0f / (e + 1.0f);
}

__device__ __forceinline__ void load_lds16(const void* g, void* l){
  __builtin_amdgcn_global_load_lds(
      (const __attribute__((address_space(1))) void*)g,
      (__attribute__((address_space(3))) void*)l, 16, 0, 0);
}

// ---------------- Wc f32 -> bf16 ----------------
__global__ __launch_bounds__(256)
void k_conv(const float* __restrict__ src, bf16_t* __restrict__ dst){
  size_t i = ((size_t)blockIdx.x * 256 + threadIdx.x) * 4;
  float4 v = *(const float4*)(src + i);
  bf16x4 o = { f2bf(v.x), f2bf(v.y), f2bf(v.z), f2bf(v.w) };
  *(bf16x4*)(dst + i) = o;
}

// ---------------- ctx f32 -> bf16 (8 elems/thread) ----------------
__global__ __launch_bounds__(256)
void k_convctx(const float* __restrict__ src, bf16_t* __restrict__ dst){
  size_t i = ((size_t)blockIdx.x * 256 + threadIdx.x) * 8;
  float4 a = *(const float4*)(src + i);
  float4 b = *(const float4*)(src + i + 4);
  bf16x8 o = { f2bf(a.x), f2bf(a.y), f2bf(a.z), f2bf(a.w),
               f2bf(b.x), f2bf(b.y), f2bf(b.z), f2bf(b.w) };
  *(bf16x8*)(dst + i) = o;
}

// ---------------- qp = query @ Wq^T + bq  (f32, 32x32 tiles) ----------------
__global__ __launch_bounds__(256)
void k_qp(const float* __restrict__ query, const float* __restrict__ Wq,
          const float* __restrict__ bq, float* __restrict__ qp){
  __shared__ float qs[32][36];
  __shared__ float wsm[32][36];
  const u32 t  = threadIdx.x;
  const u32 e0 = blockIdx.x * 32, b0 = blockIdx.y * 32;
  const u32 r  = t >> 3, ci = (t & 7) * 4;
  const u32 tm = (t >> 4) * 2, tn = (t & 15) * 2;
  float c00 = 0.f, c01 = 0.f, c10 = 0.f, c11 = 0.f;
  for (u32 k0 = 0; k0 < QD; k0 += 32){
    float4 qv = *(const float4*)(query + (size_t)(b0 + r) * QD + k0 + ci);
    float4 wv = *(const float4*)(Wq    + (size_t)(e0 + r) * QD + k0 + ci);
    __syncthreads();
    *(float4*)&qs[r][ci]  = qv;
    *(float4*)&wsm[r][ci] = wv;
    __syncthreads();
    #pragma unroll
    for (int kq = 0; kq < 8; kq++){
      float4 a0 = *(const float4*)&qs[tm][kq*4];
      float4 a1 = *(const float4*)&qs[tm+1][kq*4];
      float4 b0v = *(const float4*)&wsm[tn][kq*4];
      float4 b1v = *(const float4*)&wsm[tn+1][kq*4];
      c00 += a0.x*b0v.x + a0.y*b0v.y + a0.z*b0v.z + a0.w*b0v.w;
      c01 += a0.x*b1v.x + a0.y*b1v.y + a0.z*b1v.z + a0.w*b1v.w;
      c10 += a1.x*b0v.x + a1.y*b0v.y + a1.z*b0v.z + a1.w*b0v.w;
      c11 += a1.x*b1v.x + a1.y*b1v.y + a1.z*b1v.z + a1.w*b1v.w;
    }
  }
  float bq0 = bq[e0+tn], bq1 = bq[e0+tn+1];
  qp[(size_t)(b0+tm  )*NE + e0+tn  ] = c00 + bq0;
  qp[(size_t)(b0+tm  )*NE + e0+tn+1] = c01 + bq1;
  qp[(size_t)(b0+tm+1)*NE + e0+tn  ] = c10 + bq0;
  qp[(size_t)(b0+tm+1)*NE + e0+tn+1] = c11 + bq1;
}

// ================= 8-phase 256x256 main GEMM + fused epilogue =================
// LDS K-loop: buf b at b*65536: A rows 0..255 @0 (row stride 128 B, XOR-swz),
//             B rows 0..255 @32768. Epilogue overlay: comb[256][256] bf16 swz @0;
//             qps[3][256] f32 @131072; bcs[256] f32 @134144. Total 135168 B.
#define NKT 32   // 2048/64

__global__ __launch_bounds__(512, 2)
void k_main8(const bf16_t* __restrict__ ctxb, const bf16_t* __restrict__ wcb,
             const float* __restrict__ qp, const float* __restrict__ bcv,
             const float* __restrict__ Wo, float* __restrict__ attn)
{
  __shared__ char smem[135168] __attribute__((aligned(128)));

  const u32 tid  = threadIdx.x;
  const u32 lane = tid & 63;
  const u32 w    = tid >> 6;          // wave 0..7
  const u32 q    = lane >> 4;         // 0..3
  const u32 r15  = lane & 15;
  const u32 x7   = r15 & 7;           // read-side XOR

  // bijective XCD swizzle: grid 784 = 8 * 98
  u32 d  = blockIdx.x;
  u32 wg = (d & 7) * 98u + (d >> 3);
  const u32 ms = wg >> 2;             // 0..195
  const u32 ec = wg & 3;              // 0..3
  const u32 m0 = ms * 256;
  const u32 e0 = ec * 256;

  // staging: thread covers rows srow, srow+64 of a 128-row half; phys slot lane&7;
  // source 16B-quarter = slot ^ (row&7)  (both-sides involution)
  const u32 srow = w*8 + (lane>>3);                      // 0..63
  const u32 scol = ((lane&7) ^ ((lane>>3)&7)) * 8;       // source elem offset
  const u32 sdst = w*1024u + lane*16u;

  const u32 arow = (w>>1)*32 + r15;   // A-frag row base within quadrant
  const u32 brow = (w&1)*64 + r15;    // B-frag row base within quadrant

  // per-half staging source pointers (advance by kn*64 each call)
  const bf16_t* pA0 = ctxb + (size_t)(m0 + srow) * CD + scol;
  const bf16_t* pA1 = pA0 + (size_t)128 * CD;
  const bf16_t* pB0 = wcb  + (size_t)(e0 + srow) * CD + scol;
  const bf16_t* pB1 = pB0 + (size_t)128 * CD;

  f32x4 acc[2][2][8];
  #pragma unroll
  for (int a1 = 0; a1 < 2; a1++)
    #pragma unroll
    for (int a2 = 0; a2 < 2; a2++)
      #pragma unroll
      for (int a3 = 0; a3 < 8; a3++) acc[a1][a2][a3] = (f32x4){0.f,0.f,0.f,0.f};

  auto stage = [&](const bf16_t* src, u32 dstoff){
    load_lds16(src,                 smem + dstoff);
    load_lds16(src + (size_t)64*CD, smem + dstoff + 8192);
  };

  // prologue: tile0's A0,B0,A1,B1 (issue order matters for vmcnt)
  stage(pA0, 0u     + sdst);
  stage(pB0, 32768u + sdst);
  stage(pA1, 16384u + sdst);
  stage(pB1, 49152u + sdst);
  asm volatile("s_waitcnt vmcnt(4)" ::: "memory");   // A0(0),B0(0) resident
  __builtin_amdgcn_s_barrier();

  bf16x8 afr[2][2], bfr[4][2];

#define LOAD_A(QM) do{                                                          \
    _Pragma("unroll")                                                           \
    for (int m2 = 0; m2 < 2; m2++)                                              \
      _Pragma("unroll")                                                         \
      for (int kk = 0; kk < 2; kk++)                                            \
        afr[m2][kk] = *(const bf16x8*)(Ab_ + ((QM)*128u + arow + m2*16u)*128u   \
                                           + (((u32)(kk*4) + q) ^ x7)*16u);     \
  }while(0)

#define LOAD_B(QN) do{                                                          \
    _Pragma("unroll")                                                           \
    for (int nt = 0; nt < 4; nt++)                                              \
      _Pragma("unroll")                                                         \
      for (int kk = 0; kk < 2; kk++)                                            \
        bfr[nt][kk] = *(const bf16x8*)(Bb_ + ((QN)*128u + brow + nt*16u)*128u   \
                                           + (((u32)(kk*4) + q) ^ x7)*16u);     \
  }while(0)

#define MFMA16(QM, QN) do{                                                      \
    __builtin_amdgcn_s_setprio(1);                                              \
    _Pragma("unroll")                                                           \
    for (int m2 = 0; m2 < 2; m2++)                                              \
      _Pragma("unroll")                                                         \
      for (int nt = 0; nt < 4; nt++)                                            \
        _Pragma("unroll")                                                       \
        for (int kk = 0; kk < 2; kk++)                                          \
          acc[QM][QN][m2*4+nt] = __builtin_amdgcn_mfma_f32_16x16x32_bf16(       \
              afr[m2][kk], bfr[nt][kk], acc[QM][QN][m2*4+nt], 0, 0, 0);         \
    __builtin_amdgcn_s_setprio(0);                                              \
  }while(0)

#define VMGATE asm volatile("s_waitcnt vmcnt(4)" ::: "memory")
#define BAR    __builtin_amdgcn_s_barrier()

  for (u32 kt = 0; kt < NKT; kt++){
    const char* Ab_ = smem + (kt & 1) * 65536u;
    const char* Bb_ = Ab_ + 32768u;
    const u32 kn = ((kt + 1 < NKT) ? (kt + 1) : (NKT - 1)) * 64u;
    const u32 bo = ((kt + 1) & 1) * 65536u + sdst;

    // p0: (0,0) — read A0+B0 (12), stage A0(kt+1), gate A1(kt)
    LOAD_A(0); LOAD_B(0);
    stage(pA0 + kn, bo + 0u);
    BAR;  MFMA16(0,0);  VMGATE;  BAR;

    // p1: (1,0) — read A1 (4), B held; stage B0(kt+1), gate B1(kt)
    LOAD_A(1);
    stage(pB0 + kn, bo + 32768u);
    BAR;  MFMA16(1,0);  VMGATE;  BAR;

    // p2: (1,1) — read B1 (8), A held; stage A1(kt+1)
    LOAD_B(1);
    stage(pA1 + kn, bo + 16384u);
    BAR;  MFMA16(1,1);  BAR;

    // p3: (0,1) — re-read A0 (4), B held; stage B1(kt+1), gate A0,B0(kt+1)
    LOAD_A(0);
    stage(pB1 + kn, bo + 49152u);
    BAR;  MFMA16(0,1);  VMGATE;  BAR;
  }
#undef LOAD_A
#undef LOAD_B
#undef MFMA16
#undef VMGATE
#undef BAR

  // drain outstanding (dummy) DMAs before overlaying LDS
  asm volatile("s_waitcnt vmcnt(0)" ::: "memory");
  __syncthreads();

  // ---------------- epilogue: tanh + attn partial ----------------
  float*  qps  = (float*)(smem + 131072);   // [3][256]
  float*  bcs  = (float*)(smem + 134144);   // [256]
  const u32 b0   = m0 / 196u;
  const u32 bnd1 = (b0 + 1) * 196u - m0;
  const u32 bnd2 = bnd1 + 196u;

  for (u32 idx = tid; idx < 768; idx += 512){
    u32 bb = b0 + idx / 256u;
    if (bb > NB - 1) bb = NB - 1;
    qps[idx] = qp[(size_t)bb * NE + e0 + (idx & 255u)];
  }
  if (tid < 256) bcs[tid] = bcv[e0 + tid];

  // Wo fragments: A-operand rows g=r15 (<8 valid), k=e
  bf16x8 wf[8];
  {
    u32 g = r15;
    #pragma unroll
    for (int kk = 0; kk < 8; kk++){
      #pragma unroll
      for (int rr = 0; rr < 8; rr++){
        u32 ei = e0 + kk*32 + q*8 + rr;
        float v = (g < NG) ? Wo[(size_t)g * NE + ei] : 0.0f;
        wf[kk][rr] = f2bf(v);
      }
    }
  }
  __syncthreads();

  // tanh(cp + qp + bc) -> comb (swizzled [256][256] bf16 over smem base)
  #pragma unroll
  for (int qm = 0; qm < 2; qm++)
    #pragma unroll
    for (int qn = 0; qn < 2; qn++)
      #pragma unroll
      for (int t = 0; t < 8; t++){
        u32 rowb = qm*128u + (w>>1)*32u + (t>>2)*16u + q*4u;
        u32 col  = qn*128u + (w&1)*64u + (t&3)*16u + r15;
        float qb = bcs[col];
        #pragma unroll
        for (int r = 0; r < 4; r++){
          u32 row = rowb + r;
          u32 bidx = (row >= bnd1 ? 1u : 0u) + (row >= bnd2 ? 1u : 0u);
          float v = fast_tanh(acc[qm][qn][t][r] + qps[bidx*256u + col] + qb);
          u32 phys = (col >> 3) ^ (row & 7);
          *(bf16_t*)(smem + row*512u + phys*16u + (col&7)*2u) = f2bf(v);
        }
      }
  __syncthreads();

  // attn^T[g][n] = sum_e Wo[g,e]*comb[n,e]; 2 row-tiles of 16 per wave
  #pragma unroll
  for (int i = 0; i < 2; i++){
    u32 nrow = w*32u + i*16u + r15;
    f32x4 at = (f32x4){0.f,0.f,0.f,0.f};
    #pragma unroll
    for (int kk = 0; kk < 8; kk++){
      u32 phys = ((u32)(kk*4) + q) ^ (nrow & 7);
      bf16x8 cf = *(const bf16x8*)(smem + nrow*512u + phys*16u);
      at = __builtin_amdgcn_mfma_f32_16x16x32_bf16(wf[kk], cf, at, 0, 0, 0);
    }
    if (q < 2){
      u32 mrow = m0 + nrow;
      u32 bb = mrow / 196u;
      u32 nn = mrow - bb * 196u;
      #pragma unroll
      for (int r = 0; r < 4; r++){
        u32 g = q*4 + r;
        atomicAdd(&attn[((size_t)bb * NG + g) * NN + nn], at[r]);
      }
    }
  }
}

// ---------------- SLOW fallback main (reg-staged f32 ctx, 128 tile) ----------
#define BM 128
#define BN 128
#define BK 32
#define KSTEPS (CD/BK)

__global__ __launch_bounds__(256, 2)
void k_main_slow(const float* __restrict__ ctx, const bf16_t* __restrict__ wcb,
                 const float* __restrict__ qp, const float* __restrict__ bcv,
                 const float* __restrict__ Wo, float* __restrict__ attn)
{
  __shared__ char smem[40960] __attribute__((aligned(16)));
  const u32 tid  = threadIdx.x;
  const u32 lane = tid & 63;
  const u32 wave = tid >> 6;
  const u32 wm   = wave >> 1;
  const u32 wn   = wave & 1;
  u32 d  = blockIdx.x;
  u32 x  = d & 7;
  u32 s  = d >> 3;
  u32 ec = s & 7;
  u32 j  = s >> 3;
  u32 ms = j * 8 + x;
  const u32 m0 = ms * BM;
  const u32 e0 = ec * BN;
  const u32 ar  = tid >> 3;
  const u32 ac  = (tid & 7) * 4;
  const u32 br  = tid >> 2;
  const u32 bc8 = (tid & 3) * 8;
  const float*  actx = ctx + (size_t)m0 * CD;
  const bf16_t* bwc  = wcb + (size_t)e0 * CD;
  float4 av[4];
  uint4  bv[2];
  f32x4 acc[4][4];
  #pragma unroll
  for (int i = 0; i < 4; i++)
    #pragma unroll
    for (int jn = 0; jn < 4; jn++) acc[i][jn] = (f32x4){0.f,0.f,0.f,0.f};
  auto issue = [&](u32 ks){
    const u32 k0 = ks * BK;
    #pragma unroll
    for (int p = 0; p < 4; p++)
      av[p] = *(const float4*)(actx + (size_t)(ar + p*32) * CD + k0 + ac);
    #pragma unroll
    for (int p = 0; p < 2; p++)
      bv[p] = *(const uint4*)(bwc + (size_t)(br + p*64) * CD + k0 + bc8);
  };
  auto writebuf = [&](u32 buf){
    bf16_t* A  = (bf16_t*)(smem + buf * 10240u);
    bf16_t* Bb = (bf16_t*)(smem + 20480u + buf * 10240u);
    #pragma unroll
    for (int p = 0; p < 4; p++){
      bf16x4 o = { f2bf(av[p].x), f2bf(av[p].y), f2bf(av[p].z), f2bf(av[p].w) };
      *(bf16x4*)&A[(ar + p*32)*40 + ac] = o;
    }
    #pragma unroll
    for (int p = 0; p < 2; p++)
      *(uint4*)&Bb[(br + p*64)*40 + bc8] = bv[p];
  };
  auto compute = [&](u32 buf){
    bf16_t* A  = (bf16_t*)(smem + buf * 10240u);
    bf16_t* Bb = (bf16_t*)(smem + 20480u + buf * 10240u);
    const u32 kb = (lane >> 4) * 8;
    const u32 rm = wm*64 + (lane & 15);
    const u32 rn = wn*64 + (lane & 15);
    bf16x8 af[4], bfr[4];
    #pragma unroll
    for (int mt = 0; mt < 4; mt++) af[mt]  = *(const bf16x8*)&A[(rm + mt*16)*40 + kb];
    #pragma unroll
    for (int nt = 0; nt < 4; nt++) bfr[nt] = *(const bf16x8*)&Bb[(rn + nt*16)*40 + kb];
    #pragma unroll
    for (int mt = 0; mt < 4; mt++)
      #pragma unroll
      for (int nt = 0; nt < 4; nt++)
        acc[mt][nt] = __builtin_amdgcn_mfma_f32_16x16x32_bf16(af[mt], bfr[nt], acc[mt][nt], 0, 0, 0);
  };
  issue(0); writebuf(0);
  __syncthreads();
  for (u32 ks = 0; ks < KSTEPS; ks++){
    if (ks + 1 < KSTEPS) issue(ks + 1);
    compute(ks & 1);
    __syncthreads();
    if (ks + 1 < KSTEPS){
      writebuf((ks + 1) & 1);
      __syncthreads();
    }
  }
  float*  qp0  = (float*)(smem + 35840);
  float*  qp1  = (float*)(smem + 36352);
  float*  bcs  = (float*)(smem + 36864);
  bf16_t* comb = (bf16_t*)smem;
  const u32 b0  = m0 / 196u;
  const u32 bnd = (b0 + 1) * 196u - m0;
  if (tid < 128){
    qp0[tid] = qp[(size_t)b0 * NE + e0 + tid];
    bcs[tid] = bcv[e0 + tid];
  } else {
    u32 b1 = b0 + 1; if (b1 >= NB) b1 = NB - 1;
    qp1[tid - 128] = qp[(size_t)b1 * NE + e0 + (tid - 128)];
  }
  bf16x8 wf[4];
  {
    u32 g = lane & 15;
    #pragma unroll
    for (int kk = 0; kk < 4; kk++){
      #pragma unroll
      for (int rr = 0; rr < 8; rr++){
        u32 ei = e0 + kk*32 + (lane >> 4)*8 + rr;
        float v = (g < NG) ? Wo[(size_t)g * NE + ei] : 0.0f;
        wf[kk][rr] = f2bf(v);
      }
    }
  }
  __syncthreads();
  #pragma unroll
  for (int nt = 0; nt < 4; nt++){
    u32 el = wn*64 + nt*16 + (lane & 15);
    float qa = qp0[el];
    float qb = qp1[el];
    float bcx = bcs[el];
    #pragma unroll
    for (int mt = 0; mt < 4; mt++){
      u32 rl = wm*64 + mt*16 + (lane >> 4)*4;
      #pragma unroll
      for (int r = 0; r < 4; r++){
        u32 row = rl + r;
        float qv = (row >= bnd) ? qb : qa;
        float t = fast_tanh(acc[mt][nt][r] + qv + bcx);
        comb[row*136 + el] = f2bf(t);
      }
    }
  }
  __syncthreads();
  #pragma unroll
  for (int i = 0; i < 2; i++){
    u32 nrow = (wave*2 + i)*16 + (lane & 15);
    f32x4 at = (f32x4){0.f,0.f,0.f,0.f};
    #pragma unroll
    for (int kk = 0; kk < 4; kk++){
      bf16x8 cf = *(const bf16x8*)&comb[nrow*136 + kk*32 + (lane >> 4)*8];
      at = __builtin_amdgcn_mfma_f32_16x16x32_bf16(wf[kk], cf, at, 0, 0, 0);
    }
    if ((lane >> 4) < 2){
      u32 mrow = m0 + nrow;
      u32 bb = mrow / 196u;
      u32 nn = mrow - bb * 196u;
      #pragma unroll
      for (int r = 0; r < 4; r++){
        u32 g = (lane >> 4)*4 + r;
        atomicAdd(&attn[((size_t)bb * NG + g) * NN + nn], at[r]);
      }
    }
  }
}

// ---------------- softmax over n per (b,g) ----------------
__global__ __launch_bounds__(256)
void k_softmax(float* __restrict__ attn){
  u32 flat = blockIdx.x * 4 + (threadIdx.x >> 6);
  u32 lane = threadIdx.x & 63;
  float* row = attn + (size_t)flat * NN;
  float v0 = row[lane];
  float v1 = row[lane + 64];
  float v2 = row[lane + 128];
  float v3 = (lane < 4) ? row[lane + 192] : -1e30f;
  float m = fmaxf(fmaxf(v0, v1), fmaxf(v2, v3));
  #pragma unroll
  for (int o = 1; o < 64; o <<= 1) m = fmaxf(m, __shfl_xor(m, o));
  float e0 = __expf(v0 - m), e1 = __expf(v1 - m), e2 = __expf(v2 - m);
  float e3 = (lane < 4) ? __expf(v3 - m) : 0.f;
  float sum = e0 + e1 + e2 + e3;
  #pragma unroll
  for (int o = 1; o < 64; o <<= 1) sum += __shfl_xor(sum, o);
  float inv = 1.0f / sum;
  row[lane]       = e0 * inv;
  row[lane + 64]  = e1 * inv;
  row[lane + 128] = e2 * inv;
  if (lane < 4) row[lane + 192] = e3 * inv;
}

// ---------------- glimpse: out[b,g,c] = sum_n w[b,g,n]*ctx[b,n,c] ----------------
__global__ __launch_bounds__(256)
void k_glimpse(const float* __restrict__ ctx, const float* __restrict__ w,
               float* __restrict__ out){
  const u32 b  = blockIdx.y;
  const u32 c0 = blockIdx.x * 512 + threadIdx.x * 2;
  __shared__ float ws_[NG * NN];
  for (u32 i = threadIdx.x; i < NG * NN; i += 256)
    ws_[i] = w[(size_t)b * NG * NN + i];
  __syncthreads();
  const float* cp = ctx + (size_t)b * NN * CD + c0;
  float2 acc[NG];
  #pragma unroll
  for (int g = 0; g < NG; g++) acc[g] = make_float2(0.f, 0.f);
  for (u32 n = 0; n < NN; n++){
    float2 v = *(const float2*)(cp + (size_t)n * CD);
    #pragma unroll
    for (int g = 0; g < NG; g++){
      float wv = ws_[g * NN + n];
      acc[g].x = fmaf(wv, v.x, acc[g].x);
      acc[g].y = fmaf(wv, v.y, acc[g].y);
    }
  }
  #pragma unroll
  for (int g = 0; g < NG; g++)
    *(float2*)(out + (size_t)b * (NG * CD) + (size_t)g * CD + c0) = acc[g];
}

extern "C" void kernel_launch(void* const* d_in, const int* in_sizes, int n_in,
                              void* d_out, int out_size, void* d_ws, size_t ws_size,
                              hipStream_t stream)
{
  const float* ctx   = (const float*)d_in[0];
  const float* query = (const float*)d_in[1];
  const float* Wq    = (const float*)d_in[2];
  const float* bq    = (const float*)d_in[3];
  const float* Wc    = (const float*)d_in[4];
  const float* bc    = (const float*)d_in[5];
  const float* Wo    = (const float*)d_in[6];
  // d_in[7] = bo: constant over softmax axis -> cancels, unused.

  char* ws = (char*)d_ws;
  float*  qp   = (float*)(ws + WS_QP);
  float*  attn = (float*)(ws + WS_ATTN);
  bf16_t* wcb  = (bf16_t*)(ws + WS_WCB);
  bf16_t* ctxb = (bf16_t*)(ws + WS_CTXB);
  float*  out  = (float*)d_out;

  (void)hipMemsetAsync(attn, 0, (size_t)NB * NG * NN * 4, stream);
  k_conv<<<2048, 256, 0, stream>>>(Wc, wcb);
  k_qp<<<dim3(32, 8), 256, 0, stream>>>(query, Wq, bq, qp);

  if (ws_size >= (size_t)WS_NEED){
    k_convctx<<<50176, 256, 0, stream>>>(ctx, ctxb);
    k_main8<<<784, 512, 0, stream>>>(ctxb, wcb, qp, bc, Wo, attn);
  } else {
    k_main_slow<<<3136, 256, 0, stream>>>(ctx, wcb, qp, bc, Wo, attn);
  }

  k_softmax<<<512, 256, 0, stream>>>(attn);
  k_glimpse<<<dim3(4, 256), 256, 0, stream>>>(ctx, attn, out);
}